// Round 2
// baseline (398.323 us; speedup 1.0000x reference)
//
#include <hip/hip_runtime.h>

// Problem constants (from reference)
#define BB 4096
#define TT 16
#define HH 768
#define AA 128
#define VV 16
#define LL 2

// One block per batch row. 256 threads = 4 waves. All data fp32.
__global__ __launch_bounds__(256) void variety_adapter_kernel(
    const float* __restrict__ last_hidden,  // (B, T, H)
    const int*   __restrict__ variety_ids,  // (B,)
    const float* __restrict__ Wd,           // (V, H, A)
    const float* __restrict__ bd,           // (V, A)
    const float* __restrict__ Wu,           // (V, A, H)
    const float* __restrict__ bu,           // (V, H)
    const float* __restrict__ Wc,           // (L, H)
    const float* __restrict__ bc,           // (L,)
    float* __restrict__ out)                // (B, L)
{
    __shared__ float sx[HH];       // x_b staged
    __shared__ float sh[AA];       // gelu(down-proj)
    __shared__ float spart[256];   // partial sums
    __shared__ float sred[8];      // cross-wave reduction (4 waves x 2 logits)

    const int b = blockIdx.x;
    const int t = threadIdx.x;
    const int v = variety_ids[b];

    // ---- Stage x = last_hidden[b, 0, :] into LDS ----
    const float* xrow = last_hidden + (size_t)b * TT * HH;  // token 0
    for (int h = t; h < HH; h += 256) sx[h] = xrow[h];
    __syncthreads();

    // ---- Phase 1: h[a] = gelu(sum_h x[h] * Wd[v][h][a] + bd[v][a]) ----
    // 2 threads per output column a: thread (a, half) covers 384 h-values.
    {
        const float* wd = Wd + (size_t)v * HH * AA;
        const int a    = t & (AA - 1);
        const int half = t >> 7;            // 0 or 1
        const int h0   = half * (HH / 2);   // 0 or 384
        float acc = 0.f;
        #pragma unroll 4
        for (int h = h0; h < h0 + HH / 2; ++h) {
            acc += sx[h] * wd[(size_t)h * AA + a];   // lanes coalesced over a
        }
        spart[t] = acc;
    }
    __syncthreads();
    if (t < AA) {
        float z = spart[t] + spart[t + AA] + bd[v * AA + t];
        // tanh-approximate GELU (JAX default)
        float z3 = z * z * z;
        float g = 0.5f * z * (1.0f + tanhf(0.7978845608028654f * (z + 0.044715f * z3)));
        sh[t] = g;
    }
    __syncthreads();

    // ---- Phase 2: adapted[hh] = x[hh] + sum_a h[a]*Wu[v][a][hh] + bu[v][hh]
    //      Phase 3 fused: logits += adapted[hh] * Wc[l][hh]
    float c0, c1;
    {
        const float* wu = Wu + (size_t)v * AA * HH;
        float acc0 = 0.f, acc1 = 0.f, acc2 = 0.f;
        #pragma unroll 4
        for (int a = 0; a < AA; ++a) {
            float hv = sh[a];                        // LDS broadcast
            acc0 += hv * wu[(size_t)a * HH + t];     // lanes coalesced over hh
            acc1 += hv * wu[(size_t)a * HH + t + 256];
            acc2 += hv * wu[(size_t)a * HH + t + 512];
        }
        const float ad0 = acc0 + sx[t]       + bu[v * HH + t];
        const float ad1 = acc1 + sx[t + 256] + bu[v * HH + t + 256];
        const float ad2 = acc2 + sx[t + 512] + bu[v * HH + t + 512];

        c0 = ad0 * Wc[t]      + ad1 * Wc[t + 256]      + ad2 * Wc[t + 512];
        c1 = ad0 * Wc[HH + t] + ad1 * Wc[HH + t + 256] + ad2 * Wc[HH + t + 512];
    }

    // ---- Block reduction of (c0, c1) over 256 threads ----
    #pragma unroll
    for (int off = 32; off > 0; off >>= 1) {
        c0 += __shfl_down(c0, off);   // wave = 64 lanes
        c1 += __shfl_down(c1, off);
    }
    const int lane = t & 63;
    const int wid  = t >> 6;          // 0..3
    if (lane == 0) { sred[wid * 2 + 0] = c0; sred[wid * 2 + 1] = c1; }
    __syncthreads();
    if (t == 0) {
        float o0 = sred[0] + sred[2] + sred[4] + sred[6] + bc[0];
        float o1 = sred[1] + sred[3] + sred[5] + sred[7] + bc[1];
        out[(size_t)b * LL + 0] = o0;
        out[(size_t)b * LL + 1] = o1;
    }
}

extern "C" void kernel_launch(void* const* d_in, const int* in_sizes, int n_in,
                              void* d_out, int out_size, void* d_ws, size_t ws_size,
                              hipStream_t stream) {
    const float* last_hidden = (const float*)d_in[0];
    // d_in[1] = attention_mask (unused)
    const int*   variety_ids = (const int*)d_in[2];
    const float* Wd = (const float*)d_in[3];
    const float* bd = (const float*)d_in[4];
    const float* Wu = (const float*)d_in[5];
    const float* bu = (const float*)d_in[6];
    const float* Wc = (const float*)d_in[7];
    const float* bc = (const float*)d_in[8];
    float* out = (float*)d_out;

    variety_adapter_kernel<<<BB, 256, 0, stream>>>(
        last_hidden, variety_ids, Wd, bd, Wu, bu, Wc, bc, out);
}

// Round 3
// 299.401 us; speedup vs baseline: 1.3304x; 1.3304x over previous
//
#include <hip/hip_runtime.h>
#include <hip/hip_bf16.h>

// Problem constants
#define BB 4096
#define TT 16
#define HH 768
#define AA 128
#define VV 16
#define LL 2

typedef __attribute__((ext_vector_type(8))) short short8v;   // 8 bf16 (4 VGPRs)
typedef __attribute__((ext_vector_type(4))) float float4v;   // MFMA C/D frag

// ws layout (int/float indices into d_ws):
//  [0..16]      offs (int)            bucket offsets
//  [64..4159]   rows (int)            bucketed row ids
//  [4160..8255] Wuc  (float)          [V][A][L] = Wu@Wc^T
//  [8256..8287] buc  (float)          [V][L]    = bu@Wc^T
//  [8448.. ]    zbuf (float)          [KS][B][A] down-proj partials
#define WS_OFFS 0
#define WS_ROWS 64
#define WS_WUC  4160
#define WS_BUC  8256
#define WS_ZBUF 8448

__device__ __forceinline__ unsigned short f2bf(float f) {
    __hip_bfloat16 h = __float2bfloat16(f);   // RNE
    return *reinterpret_cast<unsigned short*>(&h);
}

__device__ __forceinline__ float gelu_tanh(float z) {
    float y = 0.7978845608028654f * (z + 0.044715f * z * z * z);
    y = fminf(fmaxf(y, -15.f), 15.f);
    float e = __expf(2.f * y);
    float th = (e - 1.f) / (e + 1.f);
    return 0.5f * z * (1.f + th);
}

// ---------------- KA: bucket rows by variety (block 16) + Wuc/buc precompute (blocks 0..15)
__global__ __launch_bounds__(256) void k_prep(
    const int*   __restrict__ variety_ids,
    const float* __restrict__ Wu,   // (V, A, H)
    const float* __restrict__ bu,   // (V, H)
    const float* __restrict__ Wc,   // (L, H)
    int* __restrict__ ws_i)
{
    const int t = threadIdx.x;
    if (blockIdx.x == 16) {
        // ---- bucketing ----
        __shared__ int hist[VV], hoff[VV + 1], hcur[VV];
        if (t < VV) hist[t] = 0;
        __syncthreads();
        for (int b = t; b < BB; b += 256) atomicAdd(&hist[variety_ids[b]], 1);
        __syncthreads();
        if (t == 0) {
            int s = 0;
            for (int i = 0; i < VV; ++i) { hoff[i] = s; s += hist[i]; }
            hoff[VV] = s;
            for (int i = 0; i <= VV; ++i) ws_i[WS_OFFS + i] = hoff[i];
        }
        __syncthreads();
        if (t < VV) hcur[t] = hoff[t];
        __syncthreads();
        for (int b = t; b < BB; b += 256) {
            int v = variety_ids[b];
            int p = atomicAdd(&hcur[v], 1);
            ws_i[WS_ROWS + p] = b;
        }
    } else {
        // ---- Wuc[v] = Wu[v] @ Wc^T ; buc[v] = bu[v] @ Wc^T ----
        const int v = blockIdx.x;
        float* Wuc = (float*)(ws_i + WS_WUC);
        float* buc = (float*)(ws_i + WS_BUC);
        if (t < AA) {
            const float* wu = Wu + (size_t)v * AA * HH + (size_t)t * HH;
            float s0 = 0.f, s1 = 0.f;
            for (int h = 0; h < HH; h += 4) {
                float4 w  = *(const float4*)&wu[h];
                float4 c0 = *(const float4*)&Wc[h];
                float4 c1 = *(const float4*)&Wc[HH + h];
                s0 += w.x * c0.x + w.y * c0.y + w.z * c0.z + w.w * c0.w;
                s1 += w.x * c1.x + w.y * c1.y + w.z * c1.z + w.w * c1.w;
            }
            Wuc[(v * AA + t) * LL + 0] = s0;
            Wuc[(v * AA + t) * LL + 1] = s1;
        } else if (t < AA + LL) {
            const int l = t - AA;
            float s = 0.f;
            const float* bv = bu + (size_t)v * HH;
            for (int h = 0; h < HH; ++h) s += bv[h] * Wc[l * HH + h];
            buc[v * LL + l] = s;
        }
    }
}

// ---------------- K4: bucketed down-proj GEMM via MFMA, K-split partials to zbuf
__global__ __launch_bounds__(256) void k_down_mfma(
    const float* __restrict__ last_hidden,
    const float* __restrict__ Wd,   // (V, H, A)
    const int*   __restrict__ ws_i,
    float* __restrict__ zbuf,
    int ks_count, int kslab)        // kslab = HH / ks_count, multiple of 128
{
    __shared__ __align__(16) unsigned short Xs[128 * 136];   // [row][k], pad 8
    __shared__ __align__(16) unsigned short Wds[128 * 136];  // [a][k]
    __shared__ int srows[128];

    const int* offs = ws_i + WS_OFFS;
    const int* rows = ws_i + WS_ROWS;
    const int t = threadIdx.x;

    // block -> (variety, row-tile, k-slice)
    const int bid = blockIdx.x;
    const int ks  = bid % ks_count;
    const int rt  = bid / ks_count;
    int v = -1, tloc = 0, cnt = 0, obase = 0, acc_t = 0;
    for (int vv = 0; vv < VV; ++vv) {
        int c  = offs[vv + 1] - offs[vv];
        int nt = (c + 127) >> 7;
        if (rt < acc_t + nt) {
            v = vv; tloc = rt - acc_t;
            cnt = c - tloc * 128; if (cnt > 128) cnt = 128;
            obase = offs[vv];
            break;
        }
        acc_t += nt;
    }
    if (v < 0) return;

    if (t < 128) {
        int rr = t < cnt ? t : cnt - 1;
        srows[t] = rows[obase + tloc * 128 + rr];
    }

    const int lane = t & 63;
    const int wv_  = t >> 6;
    const int wr = (wv_ >> 1) * 64, wc = (wv_ & 1) * 64;
    const int m = lane & 15, quad = lane >> 4;

    float4v acc[4][4];
    #pragma unroll
    for (int i = 0; i < 4; ++i)
        #pragma unroll
        for (int j = 0; j < 4; ++j)
            acc[i][j] = (float4v){0.f, 0.f, 0.f, 0.f};

    const float* wd = Wd + (size_t)v * HH * AA;
    const int nchunk = kslab >> 7;   // chunks of 128 k

    for (int kc = 0; kc < nchunk; ++kc) {
        const int ks0 = ks * kslab + kc * 128;
        __syncthreads();
        // stage X: [row][k] (k-contiguous), fp32 -> bf16
        #pragma unroll
        for (int s = 0; s < 16; ++s) {
            int idx = t + s * 256;        // 0..4095
            int r   = idx >> 5;           // 32 float4 per row
            int k4  = idx & 31;
            const float* xr = last_hidden + (size_t)srows[r] * TT * HH + ks0 + k4 * 4;
            float4 xv = *(const float4*)xr;
            unsigned int p0 = (unsigned)f2bf(xv.x) | ((unsigned)f2bf(xv.y) << 16);
            unsigned int p1 = (unsigned)f2bf(xv.z) | ((unsigned)f2bf(xv.w) << 16);
            *(uint2*)&Xs[r * 136 + k4 * 4] = make_uint2(p0, p1);
        }
        // stage Wd transposed: global [k][a] -> LDS [a][k]
        #pragma unroll
        for (int s = 0; s < 16; ++s) {
            int idx = t + s * 256;
            int hl  = idx >> 5;
            int a4  = idx & 31;
            float4 wv = *(const float4*)(wd + (size_t)(ks0 + hl) * AA + a4 * 4);
            Wds[(a4 * 4 + 0) * 136 + hl] = f2bf(wv.x);
            Wds[(a4 * 4 + 1) * 136 + hl] = f2bf(wv.y);
            Wds[(a4 * 4 + 2) * 136 + hl] = f2bf(wv.z);
            Wds[(a4 * 4 + 3) * 136 + hl] = f2bf(wv.w);
        }
        __syncthreads();

        #pragma unroll
        for (int k0 = 0; k0 < 128; k0 += 32) {
            short8v af[4], bf[4];
            #pragma unroll
            for (int i = 0; i < 4; ++i)
                af[i] = *(const short8v*)&Xs[(wr + i * 16 + m) * 136 + k0 + quad * 8];
            #pragma unroll
            for (int j = 0; j < 4; ++j)
                bf[j] = *(const short8v*)&Wds[(wc + j * 16 + m) * 136 + k0 + quad * 8];
            #pragma unroll
            for (int i = 0; i < 4; ++i)
                #pragma unroll
                for (int j = 0; j < 4; ++j)
                    acc[i][j] = __builtin_amdgcn_mfma_f32_16x16x32_bf16(af[i], bf[j], acc[i][j], 0, 0, 0);
        }
    }

    // store z partials (bucket-position indexed)
    float* zs = zbuf + (size_t)ks * BB * AA;
    #pragma unroll
    for (int i = 0; i < 4; ++i) {
        #pragma unroll
        for (int reg = 0; reg < 4; ++reg) {
            int r = wr + i * 16 + quad * 4 + reg;
            if (r < cnt) {
                size_t base = (size_t)(obase + tloc * 128 + r) * AA;
                #pragma unroll
                for (int j = 0; j < 4; ++j)
                    zs[base + wc + j * 16 + m] = acc[i][j][reg];
            }
        }
    }
}

// ---------------- K5: sum K-slices, gelu, contract with Wuc, + x@Wc^T + biases
__global__ __launch_bounds__(256) void k_combine(
    const float* __restrict__ last_hidden,
    const int*   __restrict__ ws_i,
    const float* __restrict__ bd,   // (V, A)
    const float* __restrict__ Wc,   // (L, H)
    const float* __restrict__ bc,   // (L,)
    const float* __restrict__ zbuf,
    float* __restrict__ out,
    int ks_count)
{
    const int* offs = ws_i + WS_OFFS;
    const int* rows = ws_i + WS_ROWS;
    const float* Wuc = (const float*)(ws_i + WS_WUC);
    const float* buc = (const float*)(ws_i + WS_BUC);

    const int pos  = blockIdx.x * 4 + (threadIdx.x >> 6);   // one wave per row
    const int lane = threadIdx.x & 63;
    const int gr = rows[pos];
    int v = 0;
    for (int vv = 0; vv < VV; ++vv)
        if (pos >= offs[vv] && pos < offs[vv + 1]) v = vv;

    const int a0 = lane * 2;
    float z0 = 0.f, z1 = 0.f;
    for (int ks = 0; ks < ks_count; ++ks) {
        float2 zz = *(const float2*)&zbuf[(size_t)ks * BB * AA + (size_t)pos * AA + a0];
        z0 += zz.x; z1 += zz.y;
    }
    z0 += bd[v * AA + a0];
    z1 += bd[v * AA + a0 + 1];
    float h0 = gelu_tanh(z0), h1 = gelu_tanh(z1);

    const float* wq = Wuc + (size_t)(v * AA + a0) * LL;
    float p0 = h0 * wq[0] + h1 * wq[2];
    float p1 = h0 * wq[1] + h1 * wq[3];

    const float* xr = last_hidden + (size_t)gr * TT * HH;
    #pragma unroll
    for (int s = 0; s < 12; ++s) {
        int h = lane + s * 64;
        float xv = xr[h];
        p0 += xv * Wc[h];
        p1 += xv * Wc[HH + h];
    }

    #pragma unroll
    for (int off = 32; off > 0; off >>= 1) {
        p0 += __shfl_down(p0, off);
        p1 += __shfl_down(p1, off);
    }
    if (lane == 0) {
        out[(size_t)gr * LL + 0] = p0 + bc[0] + buc[v * LL + 0];
        out[(size_t)gr * LL + 1] = p1 + bc[1] + buc[v * LL + 1];
    }
}

extern "C" void kernel_launch(void* const* d_in, const int* in_sizes, int n_in,
                              void* d_out, int out_size, void* d_ws, size_t ws_size,
                              hipStream_t stream) {
    const float* last_hidden = (const float*)d_in[0];
    const int*   variety_ids = (const int*)d_in[2];
    const float* Wd = (const float*)d_in[3];
    const float* bd = (const float*)d_in[4];
    const float* Wu = (const float*)d_in[5];
    const float* bu = (const float*)d_in[6];
    const float* Wc = (const float*)d_in[7];
    const float* bc = (const float*)d_in[8];
    float* out = (float*)d_out;

    int* ws_i = (int*)d_ws;
    float* zbuf = (float*)(ws_i + WS_ZBUF);

    // pick K-split by available workspace (zbuf slice = 2 MB)
    size_t meta_bytes = (size_t)WS_ZBUF * 4;
    size_t slice = (size_t)BB * AA * 4;
    int KS = 6;
    if (ws_size < meta_bytes + 6 * slice) KS = 3;
    if (ws_size < meta_bytes + 3 * slice) KS = 2;
    if (ws_size < meta_bytes + 2 * slice) KS = 1;
    const int kslab = HH / KS;   // 128 / 256 / 384 / 768

    k_prep<<<17, 256, 0, stream>>>(variety_ids, Wu, bu, Wc, ws_i);
    k_down_mfma<<<48 * KS, 256, 0, stream>>>(last_hidden, Wd, ws_i, zbuf, KS, kslab);
    k_combine<<<BB / 4, 256, 0, stream>>>(last_hidden, ws_i, bd, Wc, bc, zbuf, out, KS);
}

// Round 5
// 274.822 us; speedup vs baseline: 1.4494x; 1.0894x over previous
//
#include <hip/hip_runtime.h>
#include <hip/hip_bf16.h>

// Problem constants
#define BB 4096
#define TT 16
#define HH 768
#define AA 128
#define VV 16
#define LL 2
#define KS 6            // K-split: 6 slabs of 128

typedef __attribute__((ext_vector_type(8))) short short8v;   // 8 bf16 (4 VGPRs)
typedef __attribute__((ext_vector_type(4))) float float4v;   // MFMA C/D frag

// ws layout (int indices into d_ws):
//  [0..16]       offs (int)     bucket offsets
//  [64..4159]    rows (int)     bucketed row ids
//  [4160..8255]  Wuc  (float)   [V][A][L] = Wu@Wc^T
//  [8256..8287]  buc  (float)   [V][L]    = bu@Wc^T
//  [8448..]      Wdp  (ushort)  [V][KS][A][128] bf16 transposed Wd (dense)
//  [794880..]    zbuf (float)   [KS][B][A] down-proj partials
#define WS_OFFS 0
#define WS_ROWS 64
#define WS_WUC  4160
#define WS_BUC  8256
#define WS_WDP  8448
#define WS_ZBUF (8448 + (VV * KS * AA * 128) / 2)   // 8448 + 786432

__device__ __forceinline__ unsigned short f2bf(float f) {
    __hip_bfloat16 h = __float2bfloat16(f);   // RNE
    return *reinterpret_cast<unsigned short*>(&h);
}

__device__ __forceinline__ float gelu_tanh(float z) {
    float y = 0.7978845608028654f * (z + 0.044715f * z * z * z);
    y = fminf(fmaxf(y, -15.f), 15.f);
    float e = __expf(2.f * y);
    float th = (e - 1.f) / (e + 1.f);
    return 0.5f * z * (1.f + th);
}

// ---------------- K1: prep
// blocks 0..95   : Wdp[v][ks] = bf16 transpose of Wd chunk   (v=bid/6, ks=bid%6)
// blocks 96..127 : Wuc[v][a][l] = (Wu[v] @ Wc^T)[a][l]
// block 128      : buc[v][l] = bu[v] @ Wc^T
// block 129      : bucket rows by variety
__global__ __launch_bounds__(256) void k_prep(
    const int*   __restrict__ variety_ids,
    const float* __restrict__ Wd,   // (V, H, A)
    const float* __restrict__ Wu,   // (V, A, H)
    const float* __restrict__ bu,   // (V, H)
    const float* __restrict__ Wc,   // (L, H)
    int* __restrict__ ws_i)
{
    __shared__ __align__(16) unsigned short Wds[128 * 136];
    __shared__ float sp0[256], sp1[256];
    __shared__ int hist[VV], hoff[VV + 1], hcur[VV];

    const int t = threadIdx.x;
    const int bid = blockIdx.x;
    unsigned short* wdp = (unsigned short*)(ws_i + WS_WDP);
    float* Wuc = (float*)(ws_i + WS_WUC);
    float* buc = (float*)(ws_i + WS_BUC);

    if (bid < 96) {
        // ---- Wd chunk transpose + convert: global [k][a] -> Wds [a][k] ----
        const int v = bid / KS, ks = bid % KS;
        const float* wd = Wd + (size_t)v * HH * AA;
        const int ks0 = ks * 128;
        #pragma unroll
        for (int s = 0; s < 16; ++s) {
            int idx = t + s * 256;
            int hl  = idx >> 5;
            int a4  = idx & 31;
            float4 wv = *(const float4*)(wd + (size_t)(ks0 + hl) * AA + a4 * 4);
            Wds[(a4 * 4 + 0) * 136 + hl] = f2bf(wv.x);
            Wds[(a4 * 4 + 1) * 136 + hl] = f2bf(wv.y);
            Wds[(a4 * 4 + 2) * 136 + hl] = f2bf(wv.z);
            Wds[(a4 * 4 + 3) * 136 + hl] = f2bf(wv.w);
        }
        __syncthreads();
        // write out dense [a][128]: 2048 granules of 8 bf16, 16 granules/row
        unsigned short* dst = wdp + (size_t)(v * KS + ks) * AA * 128;
        #pragma unroll
        for (int s = 0; s < 8; ++s) {
            int G = t + s * 256;            // 0..2047
            int a = G >> 4, g = G & 15;     // 16 granules per 128-k row
            uint4 w = *(const uint4*)&Wds[a * 136 + g * 8];
            *(uint4*)&dst[a * 128 + g * 8] = w;
        }
    } else if (bid < 128) {
        // ---- Wuc: 64 columns per block, 4 threads per column ----
        const int v  = (bid - 96) >> 1;
        const int ah = (bid - 96) & 1;
        const int a  = ah * 64 + (t >> 2);
        const int q  = t & 3;
        const float* wu = Wu + (size_t)v * AA * HH + (size_t)a * HH;
        float s0 = 0.f, s1 = 0.f;
        #pragma unroll 4
        for (int h = q * 192; h < q * 192 + 192; h += 4) {
            float4 w  = *(const float4*)&wu[h];
            float4 c0 = *(const float4*)&Wc[h];
            float4 c1 = *(const float4*)&Wc[HH + h];
            s0 += w.x * c0.x + w.y * c0.y + w.z * c0.z + w.w * c0.w;
            s1 += w.x * c1.x + w.y * c1.y + w.z * c1.z + w.w * c1.w;
        }
        sp0[t] = s0; sp1[t] = s1;
        __syncthreads();
        if (t < 64) {
            float r0 = sp0[t * 4] + sp0[t * 4 + 1] + sp0[t * 4 + 2] + sp0[t * 4 + 3];
            float r1 = sp1[t * 4] + sp1[t * 4 + 1] + sp1[t * 4 + 2] + sp1[t * 4 + 3];
            int aa = ah * 64 + t;
            Wuc[(v * AA + aa) * LL + 0] = r0;
            Wuc[(v * AA + aa) * LL + 1] = r1;
        }
    } else if (bid == 128) {
        // ---- buc[v][l] : 32 pairs x 8 h-segments ----
        const int pair = t >> 3, seg = t & 7;
        const int v = pair >> 1, l = pair & 1;
        float s = 0.f;
        const float* bv = bu + (size_t)v * HH;
        for (int h = seg * 96; h < seg * 96 + 96; ++h) s += bv[h] * Wc[l * HH + h];
        sp0[t] = s;
        __syncthreads();
        if (t < 32) {
            float r = 0.f;
            #pragma unroll
            for (int i = 0; i < 8; ++i) r += sp0[t * 8 + i];
            buc[t] = r;   // t = v*2 + l
        }
    } else {
        // ---- bucketing ----
        if (t < VV) hist[t] = 0;
        __syncthreads();
        for (int b = t; b < BB; b += 256) atomicAdd(&hist[variety_ids[b]], 1);
        __syncthreads();
        if (t == 0) {
            int s = 0;
            for (int i = 0; i < VV; ++i) { hoff[i] = s; s += hist[i]; }
            hoff[VV] = s;
            for (int i = 0; i <= VV; ++i) ws_i[WS_OFFS + i] = hoff[i];
        }
        __syncthreads();
        if (t < VV) hcur[t] = hoff[t];
        __syncthreads();
        for (int b = t; b < BB; b += 256) {
            int v = variety_ids[b];
            int p = atomicAdd(&hcur[v], 1);
            ws_i[WS_ROWS + p] = b;
        }
    }
}

// ---------------- K2: bucketed down-proj GEMM via MFMA (one 128-k chunk per block)
__global__ __launch_bounds__(256) void k_down_mfma(
    const float* __restrict__ last_hidden,
    const int*   __restrict__ ws_i,
    float* __restrict__ zbuf)
{
    __shared__ __align__(16) unsigned short Xs[128 * 136];   // [row][k], pad 8
    __shared__ __align__(16) unsigned short Wds[128 * 136];  // [a][k]
    __shared__ int srows[128];

    const int* offs = ws_i + WS_OFFS;
    const int* rows = ws_i + WS_ROWS;
    const unsigned short* wdp = (const unsigned short*)(ws_i + WS_WDP);
    const int t = threadIdx.x;

    const int ks = blockIdx.x % KS;
    const int rt = blockIdx.x / KS;
    int v = -1, tloc = 0, cnt = 0, obase = 0, acc_t = 0;
    for (int vv = 0; vv < VV; ++vv) {
        int c  = offs[vv + 1] - offs[vv];
        int nt = (c + 127) >> 7;
        if (rt < acc_t + nt) {
            v = vv; tloc = rt - acc_t;
            cnt = c - tloc * 128; if (cnt > 128) cnt = 128;
            obase = offs[vv];
            break;
        }
        acc_t += nt;
    }
    if (v < 0) return;

    if (t < 128) {
        int rr = t < cnt ? t : cnt - 1;
        srows[t] = rows[obase + tloc * 128 + rr];
    }
    __syncthreads();

    // stage A: X rows, fp32 -> bf16, [row][k]
    const int ks0 = ks * 128;
    #pragma unroll
    for (int s = 0; s < 16; ++s) {
        int idx = t + s * 256;
        int r   = idx >> 5;
        int k4  = idx & 31;
        const float* xr = last_hidden + (size_t)srows[r] * TT * HH + ks0 + k4 * 4;
        float4 xv = *(const float4*)xr;
        unsigned int p0 = (unsigned)f2bf(xv.x) | ((unsigned)f2bf(xv.y) << 16);
        unsigned int p1 = (unsigned)f2bf(xv.z) | ((unsigned)f2bf(xv.w) << 16);
        *(uint2*)&Xs[r * 136 + k4 * 4] = make_uint2(p0, p1);
    }
    // stage B: pre-transposed dense bf16 Wdp [a][128] -> LDS [a][k] (pad 136)
    {
        const unsigned short* wb = wdp + (size_t)(v * KS + ks) * AA * 128;
        #pragma unroll
        for (int s = 0; s < 8; ++s) {
            int G = t + s * 256;            // 0..2047
            int a = G >> 4, g = G & 15;     // 16 granules per 128-k row
            uint4 w = *(const uint4*)&wb[a * 128 + g * 8];
            *(uint4*)&Wds[a * 136 + g * 8] = w;
        }
    }
    __syncthreads();

    const int lane = t & 63;
    const int wv_  = t >> 6;
    const int wr = (wv_ >> 1) * 64, wc = (wv_ & 1) * 64;
    const int m = lane & 15, quad = lane >> 4;

    float4v acc[4][4];
    #pragma unroll
    for (int i = 0; i < 4; ++i)
        #pragma unroll
        for (int j = 0; j < 4; ++j)
            acc[i][j] = (float4v){0.f, 0.f, 0.f, 0.f};

    #pragma unroll
    for (int k0 = 0; k0 < 128; k0 += 32) {
        short8v af[4], bf[4];
        #pragma unroll
        for (int i = 0; i < 4; ++i)
            af[i] = *(const short8v*)&Xs[(wr + i * 16 + m) * 136 + k0 + quad * 8];
        #pragma unroll
        for (int j = 0; j < 4; ++j)
            bf[j] = *(const short8v*)&Wds[(wc + j * 16 + m) * 136 + k0 + quad * 8];
        #pragma unroll
        for (int i = 0; i < 4; ++i)
            #pragma unroll
            for (int j = 0; j < 4; ++j)
                acc[i][j] = __builtin_amdgcn_mfma_f32_16x16x32_bf16(af[i], bf[j], acc[i][j], 0, 0, 0);
    }

    // store z partials (bucket-position indexed)
    float* zs = zbuf + (size_t)ks * BB * AA;
    #pragma unroll
    for (int i = 0; i < 4; ++i) {
        #pragma unroll
        for (int reg = 0; reg < 4; ++reg) {
            int r = wr + i * 16 + quad * 4 + reg;
            if (r < cnt) {
                size_t base = (size_t)(obase + tloc * 128 + r) * AA;
                #pragma unroll
                for (int j = 0; j < 4; ++j)
                    zs[base + wc + j * 16 + m] = acc[i][j][reg];
            }
        }
    }
}

// ---------------- K3: sum K-slices, gelu, contract with Wuc, + x@Wc^T + biases
__global__ __launch_bounds__(256) void k_combine(
    const float* __restrict__ last_hidden,
    const int*   __restrict__ ws_i,
    const float* __restrict__ bd,   // (V, A)
    const float* __restrict__ Wc,   // (L, H)
    const float* __restrict__ bc,   // (L,)
    const float* __restrict__ zbuf,
    float* __restrict__ out)
{
    const int* offs = ws_i + WS_OFFS;
    const int* rows = ws_i + WS_ROWS;
    const float* Wuc = (const float*)(ws_i + WS_WUC);
    const float* buc = (const float*)(ws_i + WS_BUC);

    const int pos  = blockIdx.x * 4 + (threadIdx.x >> 6);   // one wave per row
    const int lane = threadIdx.x & 63;
    const int gr = rows[pos];
    int v = 0;
    for (int vv = 0; vv < VV; ++vv)
        if (pos >= offs[vv] && pos < offs[vv + 1]) v = vv;

    const int a0 = lane * 2;
    float z0 = 0.f, z1 = 0.f;
    #pragma unroll
    for (int ks = 0; ks < KS; ++ks) {
        float2 zz = *(const float2*)&zbuf[(size_t)ks * BB * AA + (size_t)pos * AA + a0];
        z0 += zz.x; z1 += zz.y;
    }
    z0 += bd[v * AA + a0];
    z1 += bd[v * AA + a0 + 1];
    float h0 = gelu_tanh(z0), h1 = gelu_tanh(z1);

    const float* wq = Wuc + (size_t)(v * AA + a0) * LL;
    float p0 = h0 * wq[0] + h1 * wq[2];
    float p1 = h0 * wq[1] + h1 * wq[3];

    const float* xr = last_hidden + (size_t)gr * TT * HH;
    #pragma unroll
    for (int s = 0; s < 12; ++s) {
        int h = lane + s * 64;
        float xv = xr[h];
        p0 += xv * Wc[h];
        p1 += xv * Wc[HH + h];
    }

    #pragma unroll
    for (int off = 32; off > 0; off >>= 1) {
        p0 += __shfl_down(p0, off);
        p1 += __shfl_down(p1, off);
    }
    if (lane == 0) {
        out[(size_t)gr * LL + 0] = p0 + bc[0] + buc[v * LL + 0];
        out[(size_t)gr * LL + 1] = p1 + bc[1] + buc[v * LL + 1];
    }
}

extern "C" void kernel_launch(void* const* d_in, const int* in_sizes, int n_in,
                              void* d_out, int out_size, void* d_ws, size_t ws_size,
                              hipStream_t stream) {
    const float* last_hidden = (const float*)d_in[0];
    const int*   variety_ids = (const int*)d_in[2];
    const float* Wd = (const float*)d_in[3];
    const float* bd = (const float*)d_in[4];
    const float* Wu = (const float*)d_in[5];
    const float* bu = (const float*)d_in[6];
    const float* Wc = (const float*)d_in[7];
    const float* bc = (const float*)d_in[8];
    float* out = (float*)d_out;

    int* ws_i = (int*)d_ws;
    float* zbuf = (float*)(ws_i + WS_ZBUF);

    k_prep<<<130, 256, 0, stream>>>(variety_ids, Wd, Wu, bu, Wc, ws_i);
    k_down_mfma<<<48 * KS, 256, 0, stream>>>(last_hidden, ws_i, zbuf);
    k_combine<<<BB / 4, 256, 0, stream>>>(last_hidden, ws_i, bd, Wc, bc, zbuf, out);
}